// Round 1
// baseline (211.936 us; speedup 1.0000x reference)
//
#include <hip/hip_runtime.h>

#define T_DIM 128
#define B_DIM 512
#define S_DIM 512
#define F_DIM 8
#define TCHUNK 16

// Kernel A: per-batch histogram of fidx = field_map[mrs[b,s]]; also zero d_out.
__global__ __launch_bounds__(256) void hist_kernel(const int* __restrict__ mrs,
                                                   const int* __restrict__ field_map,
                                                   float* __restrict__ counts,
                                                   float* __restrict__ out) {
    __shared__ int h[F_DIM + 1];
    const int b = blockIdx.x;
    const int tid = threadIdx.x;
    if (tid <= F_DIM) h[tid] = 0;
    if (b == 0 && tid == 0) out[0] = 0.0f;
    __syncthreads();
    const int base = b * S_DIM + tid * 2;
    const int f0 = field_map[mrs[base]];
    const int f1 = field_map[mrs[base + 1]];
    atomicAdd(&h[f0], 1);
    atomicAdd(&h[f1], 1);
    __syncthreads();
    if (tid < F_DIM) counts[b * F_DIM + tid] = (float)h[tid + 1];
}

// Kernel B: glut[b*T+t][0..8] = {0, gates[f,b,t] * inv_norm(t,b)}
__global__ __launch_bounds__(256) void lut_kernel(const float* __restrict__ gates,
                                                  const float* __restrict__ counts,
                                                  float* __restrict__ glut) {
    const int idx = blockIdx.x * blockDim.x + threadIdx.x;  // = b*T + t
    const int t = idx & (T_DIM - 1);
    const int b = idx >> 7;
    float g[F_DIM];
    float norm = 0.0f;
#pragma unroll
    for (int f = 0; f < F_DIM; ++f) {
        g[f] = gates[((size_t)f * B_DIM + b) * T_DIM + t];
        norm = fmaf(counts[b * F_DIM + f], g[f], norm);
    }
    const float inv = (norm == 0.0f) ? 1.0f : (1.0f / norm);
    float* o = glut + (size_t)idx * 9;
    o[0] = 0.0f;
#pragma unroll
    for (int f = 0; f < F_DIM; ++f) o[f + 1] = g[f] * inv;
}

// Kernel C: stream attention once; acc += (attn - lut[fidx])^2
__global__ __launch_bounds__(256) void loss_kernel(const float* __restrict__ attn,
                                                   const int* __restrict__ mrs,
                                                   const int* __restrict__ field_map,
                                                   const float* __restrict__ glut,
                                                   float* __restrict__ out) {
    const int b = blockIdx.x;
    const int tc = blockIdx.y;
    const int tid = threadIdx.x;
    const int s0 = tid * 2;

    // fidx is t-invariant: load once into registers.
    const int mbase = b * S_DIM + s0;
    const int f0 = field_map[mrs[mbase]];
    const int f1 = field_map[mrs[mbase + 1]];

    float acc = 0.0f;
    const int t0 = tc * TCHUNK;
    const float* arow = attn + ((size_t)t0 * B_DIM + b) * S_DIM + s0;
    const float* lrow = glut + ((size_t)b * T_DIM + t0) * 9;
#pragma unroll
    for (int i = 0; i < TCHUNK; ++i) {
        const float2 v = *(const float2*)arow;
        const float g0 = lrow[f0];
        const float g1 = lrow[f1];
        const float d0 = v.x - g0;
        const float d1 = v.y - g1;
        acc = fmaf(d0, d0, acc);
        acc = fmaf(d1, d1, acc);
        arow += (size_t)B_DIM * S_DIM;
        lrow += 9;
    }

    // wave reduce (64 lanes) then cross-wave via LDS
#pragma unroll
    for (int off = 32; off > 0; off >>= 1) acc += __shfl_down(acc, off);
    __shared__ float wsum[4];
    if ((tid & 63) == 0) wsum[tid >> 6] = acc;
    __syncthreads();
    if (tid == 0) {
        const float s = (wsum[0] + wsum[1]) + (wsum[2] + wsum[3]);
        atomicAdd(out, s * (1.0f / ((float)T_DIM * (float)B_DIM * (float)S_DIM)));
    }
}

extern "C" void kernel_launch(void* const* d_in, const int* in_sizes, int n_in,
                              void* d_out, int out_size, void* d_ws, size_t ws_size,
                              hipStream_t stream) {
    const float* attention = (const float*)d_in[0];   // [T,B,S] f32
    const float* gates     = (const float*)d_in[1];   // [F,B,T] f32
    const int*   mrs       = (const int*)d_in[2];     // [B,S] i32
    const int*   field_map = (const int*)d_in[3];     // [V] i32
    float* out = (float*)d_out;

    float* counts = (float*)d_ws;                       // B*F floats = 16 KiB
    float* glut   = (float*)((char*)d_ws + 16384);      // B*T*9 floats ≈ 2.25 MiB

    hist_kernel<<<dim3(B_DIM), dim3(256), 0, stream>>>(mrs, field_map, counts, out);
    lut_kernel<<<dim3((B_DIM * T_DIM) / 256), dim3(256), 0, stream>>>(gates, counts, glut);
    loss_kernel<<<dim3(B_DIM, T_DIM / TCHUNK), dim3(256), 0, stream>>>(attention, mrs, field_map,
                                                                       glut, out);
}

// Round 2
// 210.239 us; speedup vs baseline: 1.0081x; 1.0081x over previous
//
#include <hip/hip_runtime.h>

#define T_DIM 128
#define B_DIM 512
#define S_DIM 512
#define F_DIM 8
#define TCHUNK 16

__global__ void zero_kernel(float* __restrict__ out) { out[0] = 0.0f; }

// One block per (b, t-chunk). Histogram + LUT build in LDS, then a single
// float4 streaming pass over attention.
__global__ __launch_bounds__(256) void fused_kernel(const float* __restrict__ attn,
                                                    const float* __restrict__ gates,
                                                    const int* __restrict__ mrs,
                                                    const int* __restrict__ field_map,
                                                    float* __restrict__ out) {
    const int b = blockIdx.x;
    const int t0 = blockIdx.y * TCHUNK;
    const int tid = threadIdx.x;
    const int lo = tid & 127;   // s-group: 4 floats each -> covers S=512
    const int hi = tid >> 7;    // which of 2 t-rows per pass

    __shared__ int h[F_DIM + 1];
    __shared__ float glds[F_DIM][TCHUNK];
    __shared__ float lut[TCHUNK][F_DIM + 1];
    __shared__ float wsum[4];

    if (tid <= F_DIM) h[tid] = 0;
    __syncthreads();

    // per-thread field indices; t-invariant, 4 consecutive s positions
    const int4 m = *(const int4*)(mrs + b * S_DIM + lo * 4);
    const int f0 = field_map[m.x];
    const int f1 = field_map[m.y];
    const int f2 = field_map[m.z];
    const int f3 = field_map[m.w];
    if (hi == 0) {  // count each s exactly once
        atomicAdd(&h[f0], 1);
        atomicAdd(&h[f1], 1);
        atomicAdd(&h[f2], 1);
        atomicAdd(&h[f3], 1);
    }

    // stage gates[f, b, t0..t0+15] into LDS (coalesced within each f-group)
    if (tid < F_DIM * TCHUNK) {
        const int f = tid >> 4;
        const int i = tid & 15;
        glds[f][i] = gates[((size_t)f * B_DIM + b) * T_DIM + t0 + i];
    }
    __syncthreads();

    // build per-t LUT: lut[i][0]=0, lut[i][f+1]=gates*inv_norm
    if (tid < TCHUNK) {
        float norm = 0.0f;
#pragma unroll
        for (int f = 0; f < F_DIM; ++f) norm = fmaf((float)h[f + 1], glds[f][tid], norm);
        const float inv = (norm == 0.0f) ? 1.0f : 1.0f / norm;
        lut[tid][0] = 0.0f;
#pragma unroll
        for (int f = 0; f < F_DIM; ++f) lut[tid][f + 1] = glds[f][tid] * inv;
    }
    __syncthreads();

    // main stream: 16 B/lane, 2 t-rows per 256-thread pass, 8 passes
    float acc = 0.0f;
#pragma unroll
    for (int i = 0; i < TCHUNK / 2; ++i) {
        const int t = t0 + 2 * i + hi;
        const float4 v = *(const float4*)(attn + ((size_t)t * B_DIM + b) * S_DIM + lo * 4);
        const float* L = lut[2 * i + hi];
        const float d0 = v.x - L[f0];
        const float d1 = v.y - L[f1];
        const float d2 = v.z - L[f2];
        const float d3 = v.w - L[f3];
        acc = fmaf(d0, d0, acc);
        acc = fmaf(d1, d1, acc);
        acc = fmaf(d2, d2, acc);
        acc = fmaf(d3, d3, acc);
    }

    // wave reduce (64 lanes) then cross-wave via LDS, one atomic per block
#pragma unroll
    for (int off = 32; off > 0; off >>= 1) acc += __shfl_down(acc, off);
    if ((tid & 63) == 0) wsum[tid >> 6] = acc;
    __syncthreads();
    if (tid == 0) {
        const float s = (wsum[0] + wsum[1]) + (wsum[2] + wsum[3]);
        atomicAdd(out, s * (1.0f / ((float)T_DIM * (float)B_DIM * (float)S_DIM)));
    }
}

extern "C" void kernel_launch(void* const* d_in, const int* in_sizes, int n_in,
                              void* d_out, int out_size, void* d_ws, size_t ws_size,
                              hipStream_t stream) {
    const float* attention = (const float*)d_in[0];   // [T,B,S] f32
    const float* gates     = (const float*)d_in[1];   // [F,B,T] f32
    const int*   mrs       = (const int*)d_in[2];     // [B,S] i32
    const int*   field_map = (const int*)d_in[3];     // [V] i32
    float* out = (float*)d_out;

    zero_kernel<<<dim3(1), dim3(1), 0, stream>>>(out);
    fused_kernel<<<dim3(B_DIM, T_DIM / TCHUNK), dim3(256), 0, stream>>>(attention, gates, mrs,
                                                                        field_map, out);
}